// Round 12
// baseline (111.232 us; speedup 1.0000x reference)
//
#include <hip/hip_runtime.h>
#include <stdint.h>

using ushort8 = __attribute__((ext_vector_type(8))) unsigned short;
using bf16x8  = __attribute__((ext_vector_type(8))) __bf16;
using f32x16  = __attribute__((ext_vector_type(16))) float;
using u32x4   = __attribute__((ext_vector_type(4))) uint32_t;
using us4     = __attribute__((ext_vector_type(4))) unsigned short;

#define AS1 __attribute__((address_space(1)))
#define AS3 __attribute__((address_space(3)))

__device__ __forceinline__ unsigned short f2bf(float x){
  uint32_t u = __builtin_bit_cast(uint32_t, x);
  u = (u + 0x7FFFu + ((u >> 16) & 1u)) >> 16;   // RNE
  return (unsigned short)u;
}
__device__ __forceinline__ float bf2f(unsigned short b){
  uint32_t u = ((uint32_t)b) << 16;
  return __builtin_bit_cast(float, u);
}
__device__ __forceinline__ f32x16 mfma16(bf16x8 a, bf16x8 b, f32x16 c){
  return __builtin_amdgcn_mfma_f32_32x32x16_bf16(a, b, c, 0, 0, 0);
}
__device__ __forceinline__ bf16x8 cvt8(const float* p){
  ushort8 v;
  #pragma unroll
  for (int j = 0; j < 8; ++j) v[j] = f2bf(p[j]);
  return __builtin_bit_cast(bf16x8, v);
}

// Pre-pass (verbatim from r8, verified): Wb4[s][pt][ch][granule q][8 bf16].
// Granule q = cc*64 + lg*32 + l31 holds A-frag chunk for lane (l31,lg), frag cc:
//   p = pt*32 + l31, c = ch*64 + cc*16 + lg*8 + j.
// s<128: A[p][c] = W[(s*128+p)*128+c]; s=128: A[p][i] = b[i*128+p].
__global__ void prep_wb4(const float* __restrict__ W, const float* __restrict__ bias,
                         unsigned short* __restrict__ Wb4){
  int e = blockIdx.x * 256 + threadIdx.x;
  if (e >= 129 * 16384) return;
  int jj = e & 7, q = (e >> 3) & 255, sl = (e >> 11) & 7, s = e >> 14;
  int ch = sl & 1, pt = sl >> 1;
  int cc = q >> 6, lg = (q >> 5) & 1, l31 = q & 31;
  int p = pt * 32 + l31;
  int c = ch * 64 + cc * 16 + lg * 8 + jj;
  float v = (s < 128) ? W[(s << 14) + (p << 7) + c] : bias[(c << 7) + p];
  Wb4[e] = f2bf(v);
}

// dynmlp: grid 512 = 256 token-tiles(64t) x 2 K-halves. q=(b>>2)&1 -> each XCD
// serves ONE fixed K-half (2.1MB L2 set).  512thr = 8 waves = 4 pt x 2 ch.
// Wave: 32p x 64t (F=2) x 64c; bfr(loc) register-stationary; W staged in LDS
// ONCE per WG, waves read disjoint 1KB (pt,ch)-slices -> 1KB per 8 MFMAs.
// 128 parity phases (step = (i, ch-half), 16KB); depth-3 ring; per phase:
// vmcnt(2) -> barrier (cross-wave stage-s visibility) -> stage s+2 (slot last
// read BEFORE the barrier => overwrite-safe) -> parity waves compute.
// ~110 VGPR/wave -> 2 WGs/CU, 4 waves/SIMD.  LDS 56KB/WG (2x fits 160KB).
__global__ __launch_bounds__(512, 2)
void dynmlp(const float* __restrict__ img, const float* __restrict__ loc,
            const unsigned short* __restrict__ Wb4, unsigned short* __restrict__ part){
  __shared__ __align__(16) char smem[57344];
  unsigned short* imgT = (unsigned short*)(smem + 49152);  // [64 il][64 tl] u16, 8KB
  float* ldsY = (float*)smem;                              // [64 t][129 p] f32 (epilogue)

  const int b = blockIdx.x;
  const int q  = (b >> 2) & 1;
  const int tt = ((b >> 3) << 2) | (b & 3);
  const int t0 = tt * 64;
  const int tid = threadIdx.x, lane = tid & 63, wv = tid >> 6;
  const int pt = wv >> 1, ch = wv & 1;
  const int l31 = lane & 31, lg = lane >> 5;
  const int rdOff = lg * 512 + l31 * 16;

  const char* WB = (const char*)Wb4;
  const int stPt  = tid >> 8;
  const int st255 = tid & 255;
  // staging base: + il*32768 + parity*4096 added per call
  const char* stgB = WB + (size_t)q * 64 * 32768 + (size_t)stPt * 8192 + st255 * 16;

  // STG: stage 16KB parity-half (il = KOFF rel to stgB, parity PAR) into SLOT.
  // dst flat x = j*8192 + tid*16 ; src pt-chunk = (stPt + j*2)
  #define STG(BASE, KOFF, PAR, SLOT) do { \
    const char* _sb = (BASE) + (size_t)(KOFF) * 32768 + ((PAR) << 12); \
    char* _db = smem + (SLOT) * 16384 + tid * 16; \
    __builtin_amdgcn_global_load_lds((const AS1 uint32_t*)(_sb),          (AS3 uint32_t*)(_db),        16, 0, 0); \
    __builtin_amdgcn_global_load_lds((const AS1 uint32_t*)(_sb + 16384),  (AS3 uint32_t*)(_db + 8192), 16, 0, 0); \
  } while (0)

  // ---- prologue: stage steps 0,1; fill imgT; build stationary loc frags ----
  STG(stgB, 0, 0, 0);
  STG(stgB, 0, 1, 1);

  #pragma unroll
  for (int v = 0; v < 2; ++v){
    int e2 = v * 512 + tid;
    int tl = e2 & 63, iq = e2 >> 6;            // iq 0..15
    float4 f4 = *(const float4*)&img[(size_t)(t0 + tl) * 128 + q * 64 + iq * 4];
    imgT[(iq * 4 + 0) * 64 + tl] = f2bf(f4.x);
    imgT[(iq * 4 + 1) * 64 + tl] = f2bf(f4.y);
    imgT[(iq * 4 + 2) * 64 + tl] = f2bf(f4.z);
    imgT[(iq * 4 + 3) * 64 + tl] = f2bf(f4.w);
  }

  bf16x8 bfr[2][4];
  #pragma unroll
  for (int f = 0; f < 2; ++f)
    #pragma unroll
    for (int cc = 0; cc < 4; ++cc)
      bfr[f][cc] = cvt8(&loc[(size_t)(t0 + f * 32 + l31) * 128 + ch * 64 + cc * 16 + lg * 8]);

  f32x16 acc[2];
  #pragma unroll
  for (int f = 0; f < 2; ++f)
    #pragma unroll
    for (int r = 0; r < 16; ++r) acc[f][r] = 0.0f;

  __syncthreads();                              // imgT ready; stages 0,1 drained

  const unsigned short* imgB = imgT + l31;

  #define COMPUTE(SLOT, IROW) do { \
    const char* bp = smem + (SLOT) * 16384 + pt * 4096 + rdOff; \
    u32x4 A0 = *(const u32x4*)(bp); \
    u32x4 A1 = *(const u32x4*)(bp + 1024); \
    u32x4 A2 = *(const u32x4*)(bp + 2048); \
    u32x4 A3 = *(const u32x4*)(bp + 3072); \
    float s0 = bf2f((IROW)[0]); \
    float s1 = bf2f((IROW)[32]); \
    bf16x8 a0 = __builtin_bit_cast(bf16x8, A0); \
    bf16x8 a1 = __builtin_bit_cast(bf16x8, A1); \
    bf16x8 a2 = __builtin_bit_cast(bf16x8, A2); \
    bf16x8 a3 = __builtin_bit_cast(bf16x8, A3); \
    f32x16 T = {}; \
    __builtin_amdgcn_s_setprio(1); \
    T = mfma16(a0, bfr[0][0], T); T = mfma16(a1, bfr[0][1], T); \
    T = mfma16(a2, bfr[0][2], T); T = mfma16(a3, bfr[0][3], T); \
    __builtin_amdgcn_s_setprio(0); \
    acc[0] += T * s0; \
    f32x16 U = {}; \
    __builtin_amdgcn_s_setprio(1); \
    U = mfma16(a0, bfr[1][0], U); U = mfma16(a1, bfr[1][1], U); \
    U = mfma16(a2, bfr[1][2], U); U = mfma16(a3, bfr[1][3], U); \
    __builtin_amdgcn_s_setprio(0); \
    acc[1] += U * s1; \
  } while (0)

  // phase k (within 6-block): vmcnt(2) [own stage s landed] -> barrier [all
  // waves' stage s landed] -> stage s+2 [slot read only pre-barrier] -> compute
  #define PHASE(KOFF, PAR, SSLOT, CSLOT, IOFF) do { \
    asm volatile("s_waitcnt vmcnt(2)" ::: "memory"); \
    __builtin_amdgcn_s_barrier(); \
    STG(stgB, KOFF, PAR, SSLOT); \
    if (ch == (PAR)) COMPUTE(CSLOT, imgB + (IOFF)); \
  } while (0)

  for (int blk = 0; blk < 21; ++blk){           // phases 0..125
    PHASE(1, 0, 2, 0, 0);
    PHASE(1, 1, 0, 1, 0);
    PHASE(2, 0, 1, 2, 64);
    PHASE(2, 1, 2, 0, 64);
    PHASE(3, 0, 0, 1, 128);
    PHASE(3, 1, 1, 2, 128);
    stgB += 3 * 32768;
    imgB += 192;
  }
  // phases 126,127 (il 63, slots 0,1), no staging
  asm volatile("s_waitcnt vmcnt(2)" ::: "memory");
  __builtin_amdgcn_s_barrier();
  if (ch == 0) COMPUTE(0, imgB);
  asm volatile("s_waitcnt vmcnt(0)" ::: "memory");
  __builtin_amdgcn_s_barrier();
  if (ch == 1) COMPUTE(1, imgB);

  // ---- bias (q==1): A = bias-image slice (global, L2-hot), B = img frags ----
  if (q == 1){
    const char* bb = WB + (size_t)128 * 32768 + (pt * 2 + ch) * 4096 + rdOff;
    u32x4 A0 = *(const u32x4*)(bb);
    u32x4 A1 = *(const u32x4*)(bb + 1024);
    u32x4 A2 = *(const u32x4*)(bb + 2048);
    u32x4 A3 = *(const u32x4*)(bb + 3072);
    bf16x8 a0 = __builtin_bit_cast(bf16x8, A0);
    bf16x8 a1 = __builtin_bit_cast(bf16x8, A1);
    bf16x8 a2 = __builtin_bit_cast(bf16x8, A2);
    bf16x8 a3 = __builtin_bit_cast(bf16x8, A3);
    #pragma unroll
    for (int f = 0; f < 2; ++f){
      size_t tr = (size_t)(t0 + f * 32 + l31) * 128 + ch * 64 + lg * 8;
      f32x16 T = {};
      T = mfma16(a0, cvt8(&img[tr]),      T);
      T = mfma16(a1, cvt8(&img[tr + 16]), T);
      T = mfma16(a2, cvt8(&img[tr + 32]), T);
      T = mfma16(a3, cvt8(&img[tr + 48]), T);
      acc[f] += T;
    }
  }

  // ---- epilogue: combine c-halves in LDS, coalesced bf16 partial store ----
  // C/D: col = l31 (t within frag), row r -> p = pt*32 + (r&3)+8*(r>>2)+4*lg
  __syncthreads();
  if (ch == 0){
    #pragma unroll
    for (int f = 0; f < 2; ++f){
      int t_l = f * 32 + l31;
      #pragma unroll
      for (int r = 0; r < 16; ++r){
        int p = pt * 32 + (r & 3) + 8 * (r >> 2) + 4 * lg;
        ldsY[t_l * 129 + p] = acc[f][r];
      }
    }
  }
  __syncthreads();
  if (ch == 1){
    #pragma unroll
    for (int f = 0; f < 2; ++f){
      int t_l = f * 32 + l31;
      #pragma unroll
      for (int r = 0; r < 16; ++r){
        int p = pt * 32 + (r & 3) + 8 * (r >> 2) + 4 * lg;
        ldsY[t_l * 129 + p] += acc[f][r];
      }
    }
  }
  __syncthreads();
  unsigned short* dst = part + (size_t)q * 2097152 + (size_t)t0 * 128;
  #pragma unroll
  for (int u = 0; u < 4; ++u){
    int e4 = u * 2048 + tid * 4;
    int t_l = e4 >> 7, p = e4 & 127;
    const float* s = &ldsY[t_l * 129 + p];
    us4 v = {f2bf(s[0]), f2bf(s[1]), f2bf(s[2]), f2bf(s[3])};
    *(us4*)&dst[t_l * 128 + p] = v;
  }
}

// LN kernel: y = sum of 2 bf16 partials, LayerNorm + ReLU. grid 256 x 512 thr.
__global__ __launch_bounds__(512)
void lnk(const unsigned short* __restrict__ part, const float* __restrict__ gamma,
         const float* __restrict__ beta, float* __restrict__ out){
  const int tid = threadIdx.x, lane = tid & 63, wv = tid >> 6;
  const unsigned short* p0 = part;
  const unsigned short* p1 = part + (size_t)16384 * 128;
  float g0  = gamma[lane], g1 = gamma[lane + 64];
  float be0 = beta[lane],  be1 = beta[lane + 64];
  int tb = blockIdx.x * 64 + wv * 8;
  #pragma unroll 1
  for (int k = 0; k < 8; ++k){
    size_t t = tb + k;
    size_t i0 = t * 128 + lane, i1 = i0 + 64;
    float y0 = bf2f(p0[i0]) + bf2f(p1[i0]);
    float y1 = bf2f(p0[i1]) + bf2f(p1[i1]);
    float s = y0 + y1, sq = y0 * y0 + y1 * y1;
    #pragma unroll
    for (int m = 32; m >= 1; m >>= 1){
      s  += __shfl_xor(s, m, 64);
      sq += __shfl_xor(sq, m, 64);
    }
    float mean = s * (1.0f / 128.0f);
    float var  = sq * (1.0f / 128.0f) - mean * mean;
    float rs   = rsqrtf(var + 1e-5f);
    float o0 = fmaxf((y0 - mean) * rs * g0 + be0, 0.0f);
    float o1 = fmaxf((y1 - mean) * rs * g1 + be1, 0.0f);
    out[t * 128 + lane]      = o0;
    out[t * 128 + 64 + lane] = o1;
  }
}

extern "C" void kernel_launch(void* const* d_in, const int* in_sizes, int n_in,
                              void* d_out, int out_size, void* d_ws, size_t ws_size,
                              hipStream_t stream){
  const float* img   = (const float*)d_in[0];
  const float* loc   = (const float*)d_in[1];
  const float* W     = (const float*)d_in[2];
  const float* bias  = (const float*)d_in[3];
  const float* gamma = (const float*)d_in[4];
  const float* beta  = (const float*)d_in[5];
  float* out = (float*)d_out;
  unsigned short* Wb4  = (unsigned short*)d_ws;                    // 4,227,072 B
  unsigned short* part = (unsigned short*)((char*)d_ws + 4227072); // 2 x 16384 x 128 bf16

  prep_wb4<<<8256, 256, 0, stream>>>(W, bias, Wb4);
  dynmlp<<<512, 512, 0, stream>>>(img, loc, Wb4, part);
  lnk<<<256, 512, 0, stream>>>(part, gamma, beta, out);
}